// Round 13
// baseline (399.930 us; speedup 1.0000x reference)
//
#include <hip/hip_runtime.h>

typedef float f4 __attribute__((ext_vector_type(4)));

constexpr int NN = 100000;
constexpr int NE = 1600000;
constexpr int SCAN_BLK = 1024;
constexpr int NB = (NN + SCAN_BLK - 1) / SCAN_BLK;    // 98 scan blocks

__device__ __forceinline__ f4 relu_add(f4 a, f4 b) {
    f4 s = a + b;
    s.x = fmaxf(s.x, 0.f);
    s.y = fmaxf(s.y, 0.f);
    s.z = fmaxf(s.z, 0.f);
    s.w = fmaxf(s.w, 0.f);
    return s;
}

__device__ __forceinline__ f4 bf16x4_to_f4(uint2 u) {
    f4 r;
    r.x = __uint_as_float((u.x & 0xFFFFu) << 16);
    r.y = __uint_as_float(u.x & 0xFFFF0000u);
    r.z = __uint_as_float((u.y & 0xFFFFu) << 16);
    r.w = __uint_as_float(u.y & 0xFFFF0000u);
    return r;
}

__device__ __forceinline__ unsigned short f2bf(float f) {
    unsigned u = __float_as_uint(f);
    u = (u + 0x7FFFu + ((u >> 16) & 1u)) >> 16;   // round-to-nearest-even
    return (unsigned short)u;
}

// ---------------- fallback path (used only if ws too small) -------------------

__global__ __launch_bounds__(256) void k_init(const float* __restrict__ x,
                                              const float* __restrict__ eps,
                                              float* __restrict__ out) {
    const float s = 1.0f + eps[0];
    const float4* x4 = (const float4*)x;
    float4* o4 = (float4*)out;
    const int total = NN * 16;
    for (int i = blockIdx.x * blockDim.x + threadIdx.x; i < total;
         i += gridDim.x * blockDim.x) {
        float4 v = x4[i];
        v.x *= s; v.y *= s; v.z *= s; v.w *= s;
        o4[i] = v;
    }
}

__global__ __launch_bounds__(256) void k_edges(const float* __restrict__ x,
                                               const int* __restrict__ ei,
                                               const float* __restrict__ ea,
                                               float* __restrict__ out) {
    const int* dst = ei;
    const int* src = ei + NE;
    const float4* ea4 = (const float4*)ea;
    const float4* x4 = (const float4*)x;
    const int total = NE * 16;
    for (int g = blockIdx.x * blockDim.x + threadIdx.x; g < total;
         g += gridDim.x * blockDim.x) {
        const int e = g >> 4;
        const int c = g & 15;
        const int s = src[e];
        const int d = dst[e];
        float4 a  = ea4[g];
        float4 xv = x4[s * 16 + c];
        float* base = out + d * 64 + c * 4;
        atomicAdd(base + 0, fmaxf(xv.x + a.x, 0.0f));
        atomicAdd(base + 1, fmaxf(xv.y + a.y, 0.0f));
        atomicAdd(base + 2, fmaxf(xv.z + a.z, 0.0f));
        atomicAdd(base + 3, fmaxf(xv.w + a.w, 0.0f));
    }
}

__global__ __launch_bounds__(256) void k_linear2(const float* __restrict__ W,
                                                 const float* __restrict__ bias,
                                                 float* __restrict__ out) {
    __shared__ float Ws[64 * 64];
    __shared__ float bs[64];
    for (int i = threadIdx.x; i < 1024; i += 256)
        ((float4*)Ws)[i] = ((const float4*)W)[i];
    if (threadIdx.x < 16)
        ((float4*)bs)[threadIdx.x] = ((const float4*)bias)[threadIdx.x];
    __syncthreads();

    const int l16 = threadIdx.x & 15;
    const int gid = (blockIdx.x * 256 + threadIdx.x) >> 4;
    const float4* Ws4 = (const float4*)Ws;
    float4* out4 = (float4*)out;

    const float4 h4 = out4[gid * 16 + l16];
    float4 o = ((const float4*)bs)[l16];
#pragma unroll
    for (int d = 0; d < 64; ++d) {
        const int q = d >> 2;
        const int r = d & 3;
        float hd;
        if (r == 0)      hd = __shfl(h4.x, q, 16);
        else if (r == 1) hd = __shfl(h4.y, q, 16);
        else if (r == 2) hd = __shfl(h4.z, q, 16);
        else             hd = __shfl(h4.w, q, 16);
        const float4 w = Ws4[d * 16 + l16];
        o.x = fmaf(hd, w.x, o.x);
        o.y = fmaf(hd, w.y, o.y);
        o.z = fmaf(hd, w.z, o.z);
        o.w = fmaf(hd, w.w, o.w);
    }
    out4[gid * 16 + l16] = o;
}

// ---------------- main path ----------------------------------------------------

// fused: x (fp32) -> xb (bf16) table  +  dst histogram
__global__ __launch_bounds__(256) void k_cvt_hist(const float* __restrict__ x,
                                                  const int* __restrict__ dst,
                                                  unsigned short* __restrict__ xb,
                                                  int* __restrict__ counts) {
    const int tid = blockIdx.x * blockDim.x + threadIdx.x;
    const int nthr = gridDim.x * blockDim.x;

    const float4* x4 = (const float4*)x;
    const int xtotal = NN * 16;
    for (int i = tid; i < xtotal; i += nthr) {
        const float4 v = x4[i];
        ushort4 o;
        o.x = f2bf(v.x); o.y = f2bf(v.y); o.z = f2bf(v.z); o.w = f2bf(v.w);
        ((ushort4*)xb)[i] = o;
    }

    const int4* d4 = (const int4*)dst;
    const int htotal = NE / 4;
    for (int i = tid; i < htotal; i += nthr) {
        const int4 d = d4[i];
        atomicAdd(&counts[d.x], 1);
        atomicAdd(&counts[d.y], 1);
        atomicAdd(&counts[d.z], 1);
        atomicAdd(&counts[d.w], 1);
    }
}

__global__ __launch_bounds__(256) void k_scan_block(const int* __restrict__ counts,
                                                    int* __restrict__ offsets,
                                                    int* __restrict__ bsum) {
    __shared__ int sd[256];
    const int t = threadIdx.x;
    const int base = blockIdx.x * SCAN_BLK;
    int c[4];
    int s = 0;
#pragma unroll
    for (int k = 0; k < 4; ++k) {
        const int i = base + t * 4 + k;
        c[k] = (i < NN) ? counts[i] : 0;
        s += c[k];
    }
    sd[t] = s;
    __syncthreads();
#pragma unroll
    for (int off = 1; off < 256; off <<= 1) {
        int v = (t >= off) ? sd[t - off] : 0;
        __syncthreads();
        sd[t] += v;
        __syncthreads();
    }
    int excl = sd[t] - s;
#pragma unroll
    for (int k = 0; k < 4; ++k) {
        const int i = base + t * 4 + k;
        if (i < NN) offsets[i] = excl;
        excl += c[k];
    }
    if (t == 255) bsum[blockIdx.x] = sd[255];
}

// fused scan of the 98 block sums (redundant per block) + global fixup
__global__ __launch_bounds__(256) void k_scan_finish(int* __restrict__ offsets,
                                                     const int* __restrict__ bsum,
                                                     int* __restrict__ cursor) {
    __shared__ int sd[128];
    const int t = threadIdx.x;
    if (t < 128) {
        const int v = (t < NB) ? bsum[t] : 0;
        sd[t] = v;
    }
    __syncthreads();
#pragma unroll
    for (int off = 1; off < 128; off <<= 1) {
        int u = 0;
        if (t < 128 && t >= off) u = sd[t - off];
        __syncthreads();
        if (t < 128) sd[t] += u;
        __syncthreads();
    }
    // sd now inclusive; exclusive base for block b is sd[b] - bsum[b]
    for (int i = blockIdx.x * blockDim.x + t; i < NN;
         i += gridDim.x * blockDim.x) {
        const int b = i >> 10;
        const int v = offsets[i] + sd[b] - bsum[b];
        offsets[i] = v;
        cursor[i] = v;
    }
    if (blockIdx.x == 0 && t == 0) offsets[NN] = NE;
}

// scatter {edge, src} into dst-sorted order; 4 edges per thread (R10 verified)
__global__ __launch_bounds__(256) void k_scatter(const int* __restrict__ dst,
                                                 const int* __restrict__ src,
                                                 int* __restrict__ cursor,
                                                 int2* __restrict__ ps) {
    const int4* d4 = (const int4*)dst;
    const int4* s4 = (const int4*)src;
    const int total = NE / 4;
    for (int i = blockIdx.x * blockDim.x + threadIdx.x; i < total;
         i += gridDim.x * blockDim.x) {
        const int4 d = d4[i];
        const int4 s = s4[i];
        const int e = i * 4;
        int p0 = atomicAdd(&cursor[d.x], 1);
        int p1 = atomicAdd(&cursor[d.y], 1);
        int p2 = atomicAdd(&cursor[d.z], 1);
        int p3 = atomicAdd(&cursor[d.w], 1);
        ps[p0] = make_int2(e + 0, s.x);
        ps[p1] = make_int2(e + 1, s.y);
        ps[p2] = make_int2(e + 2, s.z);
        ps[p3] = make_int2(e + 3, s.w);
    }
}

// PURE STREAMING ea (fp32) -> eab (bf16). Nontemporal source loads (via the
// ext_vector f4 type, which the builtin accepts) so the fp32 stream doesn't
// evict the bf16 destination (205 MB, L3-resident) that k_agg_lin gathers.
__global__ __launch_bounds__(256) void k_cvt_ea(const float* __restrict__ ea,
                                                unsigned short* __restrict__ eab) {
    const f4* ea4 = (const f4*)ea;
    const int total = NE * 16;   // f4 count
    for (int i = blockIdx.x * blockDim.x + threadIdx.x; i < total;
         i += gridDim.x * blockDim.x) {
        const f4 v = __builtin_nontemporal_load(&ea4[i]);
        ushort4 o;
        o.x = f2bf(v.x); o.y = f2bf(v.y); o.z = f2bf(v.z); o.w = f2bf(v.w);
        ((ushort4*)eab)[i] = o;
    }
}

// Fused per-node aggregation + self-term + linear (R11 verified).
// One node per 16-lane group, 6250 blocks exactly. Branchless unroll-4 edge
// loop; BOTH gathers bf16 (xb 12.8MB, eab 205MB — L3-resident); self-term
// exact fp32; epilogue h @ W + b with W in LDS.
__global__ __launch_bounds__(256, 4) void k_agg_lin(const float* __restrict__ x,
                                                    const unsigned short* __restrict__ xb,
                                                    const unsigned short* __restrict__ eab,
                                                    const int* __restrict__ offsets,
                                                    const int2* __restrict__ ps,
                                                    const float* __restrict__ epsp,
                                                    const float* __restrict__ W,
                                                    const float* __restrict__ bias,
                                                    float* __restrict__ out) {
    __shared__ float Ws[64 * 64];
    __shared__ float bs[64];
    for (int i = threadIdx.x; i < 1024; i += 256)
        ((float4*)Ws)[i] = ((const float4*)W)[i];
    if (threadIdx.x < 16)
        ((float4*)bs)[threadIdx.x] = ((const float4*)bias)[threadIdx.x];
    __syncthreads();

    const int l16 = threadIdx.x & 15;
    const int n = (blockIdx.x * 256 + threadIdx.x) >> 4;   // node id, < NN exact
    const float epsv = 1.0f + epsp[0];
    const f4* x4 = (const f4*)x;
    const f4* Ws4 = (const f4*)Ws;
    f4* out4 = (f4*)out;

    const int beg = offsets[n];
    const int end = offsets[n + 1];
    f4 acc = {0.f, 0.f, 0.f, 0.f};

    int j = beg;
    for (; j + 4 <= end; j += 4) {
        const int2 d0 = ps[j];
        const int2 d1 = ps[j + 1];
        const int2 d2 = ps[j + 2];
        const int2 d3 = ps[j + 3];
        const uint2 au0 = *(const uint2*)&eab[(size_t)d0.x * 64 + l16 * 4];
        const uint2 xu0 = *(const uint2*)&xb[(size_t)d0.y * 64 + l16 * 4];
        const uint2 au1 = *(const uint2*)&eab[(size_t)d1.x * 64 + l16 * 4];
        const uint2 xu1 = *(const uint2*)&xb[(size_t)d1.y * 64 + l16 * 4];
        const uint2 au2 = *(const uint2*)&eab[(size_t)d2.x * 64 + l16 * 4];
        const uint2 xu2 = *(const uint2*)&xb[(size_t)d2.y * 64 + l16 * 4];
        const uint2 au3 = *(const uint2*)&eab[(size_t)d3.x * 64 + l16 * 4];
        const uint2 xu3 = *(const uint2*)&xb[(size_t)d3.y * 64 + l16 * 4];
        acc += relu_add(bf16x4_to_f4(xu0), bf16x4_to_f4(au0));
        acc += relu_add(bf16x4_to_f4(xu1), bf16x4_to_f4(au1));
        acc += relu_add(bf16x4_to_f4(xu2), bf16x4_to_f4(au2));
        acc += relu_add(bf16x4_to_f4(xu3), bf16x4_to_f4(au3));
    }
    for (; j < end; ++j) {                   // tail (0..3 edges; also deg<4)
        const int2 d = ps[j];
        const uint2 au = *(const uint2*)&eab[(size_t)d.x * 64 + l16 * 4];
        const uint2 xu = *(const uint2*)&xb[(size_t)d.y * 64 + l16 * 4];
        acc += relu_add(bf16x4_to_f4(xu), bf16x4_to_f4(au));
    }

    // self term from exact fp32 x
    const f4 xs = x4[n * 16 + l16];
    f4 h;
    h.x = fmaf(xs.x, epsv, acc.x);
    h.y = fmaf(xs.y, epsv, acc.y);
    h.z = fmaf(xs.z, epsv, acc.z);
    h.w = fmaf(xs.w, epsv, acc.w);

    // fused linear: o[l16*4+k] = b + sum_d h[d] * W[d][l16*4+k]
    f4 o = ((const f4*)bs)[l16];
#pragma unroll
    for (int d = 0; d < 64; ++d) {
        const int q = d >> 2;
        const int r = d & 3;
        float hd;
        if (r == 0)      hd = __shfl(h.x, q, 16);
        else if (r == 1) hd = __shfl(h.y, q, 16);
        else if (r == 2) hd = __shfl(h.z, q, 16);
        else             hd = __shfl(h.w, q, 16);
        const f4 w = Ws4[d * 16 + l16];
        o.x = fmaf(hd, w.x, o.x);
        o.y = fmaf(hd, w.y, o.y);
        o.z = fmaf(hd, w.z, o.z);
        o.w = fmaf(hd, w.w, o.w);
    }
    __builtin_nontemporal_store(o, &out4[n * 16 + l16]);
}

extern "C" void kernel_launch(void* const* d_in, const int* in_sizes, int n_in,
                              void* d_out, int out_size, void* d_ws, size_t ws_size,
                              hipStream_t stream) {
    const float* x   = (const float*)d_in[0];
    const int*   ei  = (const int*)d_in[1];
    const float* ea  = (const float*)d_in[2];
    const float* eps = (const float*)d_in[3];
    const float* W   = (const float*)d_in[4];
    const float* b   = (const float*)d_in[5];
    float* out = (float*)d_out;

    const int* dst = ei;        // edge_index[0]
    const int* src = ei + NE;   // edge_index[1]

    // workspace layout: ps, xb, eab, ints
    int2* ps     = (int2*)d_ws;                        // NE          (12.8 MB)
    unsigned short* xb  = (unsigned short*)(ps + NE);  // NN*64 bf16  (12.8 MB)
    unsigned short* eab = xb + (size_t)NN * 64;        // NE*64 bf16  (204.8 MB)
    int* counts  = (int*)(eab + (size_t)NE * 64);      // NN
    int* offsets = counts + NN;                        // NN + 1
    int* cursor  = offsets + NN + 1;                   // NN
    int* bsum    = cursor + NN;                        // 128
    const size_t ws_needed = (size_t)NE * 8 + (size_t)NN * 128 +
                             (size_t)NE * 128 +
                             (size_t)(3 * NN + 1 + 128) * sizeof(int);

    if (ws_size < ws_needed) {            // insurance: atomic fallback
        k_init<<<2048, 256, 0, stream>>>(x, eps, out);
        k_edges<<<2048, 256, 0, stream>>>(x, ei, ea, out);
        k_linear2<<<NN * 16 / 256, 256, 0, stream>>>(W, b, out);
        return;
    }

    (void)hipMemsetAsync(counts, 0, (size_t)NN * sizeof(int), stream);
    k_cvt_hist<<<1024, 256, 0, stream>>>(x, dst, xb, counts);
    k_scan_block<<<NB, 256, 0, stream>>>(counts, offsets, bsum);
    k_scan_finish<<<256, 256, 0, stream>>>(offsets, bsum, cursor);
    k_scatter<<<1024, 256, 0, stream>>>(dst, src, cursor, ps);
    k_cvt_ea<<<3072, 256, 0, stream>>>(ea, eab);
    k_agg_lin<<<NN * 16 / 256, 256, 0, stream>>>(x, xb, eab, offsets, ps, eps,
                                                 W, b, out);
}

// Round 14
// 386.000 us; speedup vs baseline: 1.0361x; 1.0361x over previous
//
#include <hip/hip_runtime.h>

typedef float f4 __attribute__((ext_vector_type(4)));

constexpr int NN = 100000;
constexpr int NE = 1600000;
constexpr int SCAN_BLK = 1024;
constexpr int NB = (NN + SCAN_BLK - 1) / SCAN_BLK;    // 98 scan blocks

__device__ __forceinline__ f4 relu_add(f4 a, f4 b) {
    f4 s = a + b;
    s.x = fmaxf(s.x, 0.f);
    s.y = fmaxf(s.y, 0.f);
    s.z = fmaxf(s.z, 0.f);
    s.w = fmaxf(s.w, 0.f);
    return s;
}

__device__ __forceinline__ f4 bf16x4_to_f4(uint2 u) {
    f4 r;
    r.x = __uint_as_float((u.x & 0xFFFFu) << 16);
    r.y = __uint_as_float(u.x & 0xFFFF0000u);
    r.z = __uint_as_float((u.y & 0xFFFFu) << 16);
    r.w = __uint_as_float(u.y & 0xFFFF0000u);
    return r;
}

__device__ __forceinline__ unsigned f2bf(float f) {
    unsigned u = __float_as_uint(f);
    return (u + 0x7FFFu + ((u >> 16) & 1u)) >> 16;   // round-to-nearest-even
}

__device__ __forceinline__ unsigned pack2bf(float lo, float hi) {
    return f2bf(lo) | (f2bf(hi) << 16);
}

// ---------------- fallback path (used only if ws too small) -------------------

__global__ __launch_bounds__(256) void k_init(const float* __restrict__ x,
                                              const float* __restrict__ eps,
                                              float* __restrict__ out) {
    const float s = 1.0f + eps[0];
    const float4* x4 = (const float4*)x;
    float4* o4 = (float4*)out;
    const int total = NN * 16;
    for (int i = blockIdx.x * blockDim.x + threadIdx.x; i < total;
         i += gridDim.x * blockDim.x) {
        float4 v = x4[i];
        v.x *= s; v.y *= s; v.z *= s; v.w *= s;
        o4[i] = v;
    }
}

__global__ __launch_bounds__(256) void k_edges(const float* __restrict__ x,
                                               const int* __restrict__ ei,
                                               const float* __restrict__ ea,
                                               float* __restrict__ out) {
    const int* dst = ei;
    const int* src = ei + NE;
    const float4* ea4 = (const float4*)ea;
    const float4* x4 = (const float4*)x;
    const int total = NE * 16;
    for (int g = blockIdx.x * blockDim.x + threadIdx.x; g < total;
         g += gridDim.x * blockDim.x) {
        const int e = g >> 4;
        const int c = g & 15;
        const int s = src[e];
        const int d = dst[e];
        float4 a  = ea4[g];
        float4 xv = x4[s * 16 + c];
        float* base = out + d * 64 + c * 4;
        atomicAdd(base + 0, fmaxf(xv.x + a.x, 0.0f));
        atomicAdd(base + 1, fmaxf(xv.y + a.y, 0.0f));
        atomicAdd(base + 2, fmaxf(xv.z + a.z, 0.0f));
        atomicAdd(base + 3, fmaxf(xv.w + a.w, 0.0f));
    }
}

__global__ __launch_bounds__(256) void k_linear2(const float* __restrict__ W,
                                                 const float* __restrict__ bias,
                                                 float* __restrict__ out) {
    __shared__ float Ws[64 * 64];
    __shared__ float bs[64];
    for (int i = threadIdx.x; i < 1024; i += 256)
        ((float4*)Ws)[i] = ((const float4*)W)[i];
    if (threadIdx.x < 16)
        ((float4*)bs)[threadIdx.x] = ((const float4*)bias)[threadIdx.x];
    __syncthreads();

    const int l16 = threadIdx.x & 15;
    const int gid = (blockIdx.x * 256 + threadIdx.x) >> 4;
    const float4* Ws4 = (const float4*)Ws;
    float4* out4 = (float4*)out;

    const float4 h4 = out4[gid * 16 + l16];
    float4 o = ((const float4*)bs)[l16];
#pragma unroll
    for (int d = 0; d < 64; ++d) {
        const int q = d >> 2;
        const int r = d & 3;
        float hd;
        if (r == 0)      hd = __shfl(h4.x, q, 16);
        else if (r == 1) hd = __shfl(h4.y, q, 16);
        else if (r == 2) hd = __shfl(h4.z, q, 16);
        else             hd = __shfl(h4.w, q, 16);
        const float4 w = Ws4[d * 16 + l16];
        o.x = fmaf(hd, w.x, o.x);
        o.y = fmaf(hd, w.y, o.y);
        o.z = fmaf(hd, w.z, o.z);
        o.w = fmaf(hd, w.w, o.w);
    }
    out4[gid * 16 + l16] = o;
}

// ---------------- main path ----------------------------------------------------

// fused streaming pass: ea (fp32) -> eab (bf16), x (fp32) -> xb (bf16),
// dst histogram. Plain cached loads (NO nontemporal — R13 showed NT loads run
// at ~half rate); 32B loads + 16B packed stores per thread for the cvt loops.
__global__ __launch_bounds__(256) void k_cvt_hist(const float* __restrict__ ea,
                                                  const float* __restrict__ x,
                                                  const int* __restrict__ dst,
                                                  unsigned short* __restrict__ eab,
                                                  unsigned short* __restrict__ xb,
                                                  int* __restrict__ counts) {
    const int tid = blockIdx.x * blockDim.x + threadIdx.x;
    const int nthr = gridDim.x * blockDim.x;

    // ea conversion: 8 floats in (32B), 8 bf16 out (16B) per iteration
    const f4* ea4 = (const f4*)ea;
    uint4* eabo = (uint4*)eab;
    const int etotal = NE * 8;
    for (int i = tid; i < etotal; i += nthr) {
        const f4 a = ea4[2 * i];
        const f4 b = ea4[2 * i + 1];
        uint4 o;
        o.x = pack2bf(a.x, a.y);
        o.y = pack2bf(a.z, a.w);
        o.z = pack2bf(b.x, b.y);
        o.w = pack2bf(b.z, b.w);
        eabo[i] = o;
    }

    // x conversion
    const f4* x4 = (const f4*)x;
    uint4* xbo = (uint4*)xb;
    const int xtotal = NN * 8;
    for (int i = tid; i < xtotal; i += nthr) {
        const f4 a = x4[2 * i];
        const f4 b = x4[2 * i + 1];
        uint4 o;
        o.x = pack2bf(a.x, a.y);
        o.y = pack2bf(a.z, a.w);
        o.z = pack2bf(b.x, b.y);
        o.w = pack2bf(b.z, b.w);
        xbo[i] = o;
    }

    // dst histogram (atomics to 400KB L2-resident counts)
    const int4* d4 = (const int4*)dst;
    const int htotal = NE / 4;
    for (int i = tid; i < htotal; i += nthr) {
        const int4 d = d4[i];
        atomicAdd(&counts[d.x], 1);
        atomicAdd(&counts[d.y], 1);
        atomicAdd(&counts[d.z], 1);
        atomicAdd(&counts[d.w], 1);
    }
}

__global__ __launch_bounds__(256) void k_scan_block(const int* __restrict__ counts,
                                                    int* __restrict__ offsets,
                                                    int* __restrict__ bsum) {
    __shared__ int sd[256];
    const int t = threadIdx.x;
    const int base = blockIdx.x * SCAN_BLK;
    int c[4];
    int s = 0;
#pragma unroll
    for (int k = 0; k < 4; ++k) {
        const int i = base + t * 4 + k;
        c[k] = (i < NN) ? counts[i] : 0;
        s += c[k];
    }
    sd[t] = s;
    __syncthreads();
#pragma unroll
    for (int off = 1; off < 256; off <<= 1) {
        int v = (t >= off) ? sd[t - off] : 0;
        __syncthreads();
        sd[t] += v;
        __syncthreads();
    }
    int excl = sd[t] - s;
#pragma unroll
    for (int k = 0; k < 4; ++k) {
        const int i = base + t * 4 + k;
        if (i < NN) offsets[i] = excl;
        excl += c[k];
    }
    if (t == 255) bsum[blockIdx.x] = sd[255];
}

// fused scan of the 98 block sums (redundant per block) + global fixup
__global__ __launch_bounds__(256) void k_scan_finish(int* __restrict__ offsets,
                                                     const int* __restrict__ bsum,
                                                     int* __restrict__ cursor) {
    __shared__ int sd[128];
    const int t = threadIdx.x;
    if (t < 128) {
        const int v = (t < NB) ? bsum[t] : 0;
        sd[t] = v;
    }
    __syncthreads();
#pragma unroll
    for (int off = 1; off < 128; off <<= 1) {
        int u = 0;
        if (t < 128 && t >= off) u = sd[t - off];
        __syncthreads();
        if (t < 128) sd[t] += u;
        __syncthreads();
    }
    // sd now inclusive; exclusive base for block b is sd[b] - bsum[b]
    for (int i = blockIdx.x * blockDim.x + t; i < NN;
         i += gridDim.x * blockDim.x) {
        const int b = i >> 10;
        const int v = offsets[i] + sd[b] - bsum[b];
        offsets[i] = v;
        cursor[i] = v;
    }
    if (blockIdx.x == 0 && t == 0) offsets[NN] = NE;
}

// scatter {edge, src} into dst-sorted order; 4 edges per thread (R10 verified)
__global__ __launch_bounds__(256) void k_scatter(const int* __restrict__ dst,
                                                 const int* __restrict__ src,
                                                 int* __restrict__ cursor,
                                                 int2* __restrict__ ps) {
    const int4* d4 = (const int4*)dst;
    const int4* s4 = (const int4*)src;
    const int total = NE / 4;
    for (int i = blockIdx.x * blockDim.x + threadIdx.x; i < total;
         i += gridDim.x * blockDim.x) {
        const int4 d = d4[i];
        const int4 s = s4[i];
        const int e = i * 4;
        int p0 = atomicAdd(&cursor[d.x], 1);
        int p1 = atomicAdd(&cursor[d.y], 1);
        int p2 = atomicAdd(&cursor[d.z], 1);
        int p3 = atomicAdd(&cursor[d.w], 1);
        ps[p0] = make_int2(e + 0, s.x);
        ps[p1] = make_int2(e + 1, s.y);
        ps[p2] = make_int2(e + 2, s.z);
        ps[p3] = make_int2(e + 3, s.w);
    }
}

// Fused per-node aggregation + self-term + linear (R11 verified).
// One node per 16-lane group, 6250 blocks exactly. Branchless unroll-4 edge
// loop; BOTH gathers bf16 (xb 12.8MB, eab 205MB — L3-resident); self-term
// exact fp32; epilogue h @ W + b with W in LDS.
__global__ __launch_bounds__(256, 4) void k_agg_lin(const float* __restrict__ x,
                                                    const unsigned short* __restrict__ xb,
                                                    const unsigned short* __restrict__ eab,
                                                    const int* __restrict__ offsets,
                                                    const int2* __restrict__ ps,
                                                    const float* __restrict__ epsp,
                                                    const float* __restrict__ W,
                                                    const float* __restrict__ bias,
                                                    float* __restrict__ out) {
    __shared__ float Ws[64 * 64];
    __shared__ float bs[64];
    for (int i = threadIdx.x; i < 1024; i += 256)
        ((float4*)Ws)[i] = ((const float4*)W)[i];
    if (threadIdx.x < 16)
        ((float4*)bs)[threadIdx.x] = ((const float4*)bias)[threadIdx.x];
    __syncthreads();

    const int l16 = threadIdx.x & 15;
    const int n = (blockIdx.x * 256 + threadIdx.x) >> 4;   // node id, < NN exact
    const float epsv = 1.0f + epsp[0];
    const f4* x4 = (const f4*)x;
    const f4* Ws4 = (const f4*)Ws;
    f4* out4 = (f4*)out;

    const int beg = offsets[n];
    const int end = offsets[n + 1];
    f4 acc = {0.f, 0.f, 0.f, 0.f};

    int j = beg;
    for (; j + 4 <= end; j += 4) {
        const int2 d0 = ps[j];
        const int2 d1 = ps[j + 1];
        const int2 d2 = ps[j + 2];
        const int2 d3 = ps[j + 3];
        const uint2 au0 = *(const uint2*)&eab[(size_t)d0.x * 64 + l16 * 4];
        const uint2 xu0 = *(const uint2*)&xb[(size_t)d0.y * 64 + l16 * 4];
        const uint2 au1 = *(const uint2*)&eab[(size_t)d1.x * 64 + l16 * 4];
        const uint2 xu1 = *(const uint2*)&xb[(size_t)d1.y * 64 + l16 * 4];
        const uint2 au2 = *(const uint2*)&eab[(size_t)d2.x * 64 + l16 * 4];
        const uint2 xu2 = *(const uint2*)&xb[(size_t)d2.y * 64 + l16 * 4];
        const uint2 au3 = *(const uint2*)&eab[(size_t)d3.x * 64 + l16 * 4];
        const uint2 xu3 = *(const uint2*)&xb[(size_t)d3.y * 64 + l16 * 4];
        acc += relu_add(bf16x4_to_f4(xu0), bf16x4_to_f4(au0));
        acc += relu_add(bf16x4_to_f4(xu1), bf16x4_to_f4(au1));
        acc += relu_add(bf16x4_to_f4(xu2), bf16x4_to_f4(au2));
        acc += relu_add(bf16x4_to_f4(xu3), bf16x4_to_f4(au3));
    }
    for (; j < end; ++j) {                   // tail (0..3 edges; also deg<4)
        const int2 d = ps[j];
        const uint2 au = *(const uint2*)&eab[(size_t)d.x * 64 + l16 * 4];
        const uint2 xu = *(const uint2*)&xb[(size_t)d.y * 64 + l16 * 4];
        acc += relu_add(bf16x4_to_f4(xu), bf16x4_to_f4(au));
    }

    // self term from exact fp32 x
    const f4 xs = x4[n * 16 + l16];
    f4 h;
    h.x = fmaf(xs.x, epsv, acc.x);
    h.y = fmaf(xs.y, epsv, acc.y);
    h.z = fmaf(xs.z, epsv, acc.z);
    h.w = fmaf(xs.w, epsv, acc.w);

    // fused linear: o[l16*4+k] = b + sum_d h[d] * W[d][l16*4+k]
    f4 o = ((const f4*)bs)[l16];
#pragma unroll
    for (int d = 0; d < 64; ++d) {
        const int q = d >> 2;
        const int r = d & 3;
        float hd;
        if (r == 0)      hd = __shfl(h.x, q, 16);
        else if (r == 1) hd = __shfl(h.y, q, 16);
        else if (r == 2) hd = __shfl(h.z, q, 16);
        else             hd = __shfl(h.w, q, 16);
        const f4 w = Ws4[d * 16 + l16];
        o.x = fmaf(hd, w.x, o.x);
        o.y = fmaf(hd, w.y, o.y);
        o.z = fmaf(hd, w.z, o.z);
        o.w = fmaf(hd, w.w, o.w);
    }
    __builtin_nontemporal_store(o, &out4[n * 16 + l16]);
}

extern "C" void kernel_launch(void* const* d_in, const int* in_sizes, int n_in,
                              void* d_out, int out_size, void* d_ws, size_t ws_size,
                              hipStream_t stream) {
    const float* x   = (const float*)d_in[0];
    const int*   ei  = (const int*)d_in[1];
    const float* ea  = (const float*)d_in[2];
    const float* eps = (const float*)d_in[3];
    const float* W   = (const float*)d_in[4];
    const float* b   = (const float*)d_in[5];
    float* out = (float*)d_out;

    const int* dst = ei;        // edge_index[0]
    const int* src = ei + NE;   // edge_index[1]

    // workspace layout: ps, xb, eab, ints
    int2* ps     = (int2*)d_ws;                        // NE          (12.8 MB)
    unsigned short* xb  = (unsigned short*)(ps + NE);  // NN*64 bf16  (12.8 MB)
    unsigned short* eab = xb + (size_t)NN * 64;        // NE*64 bf16  (204.8 MB)
    int* counts  = (int*)(eab + (size_t)NE * 64);      // NN
    int* offsets = counts + NN;                        // NN + 1
    int* cursor  = offsets + NN + 1;                   // NN
    int* bsum    = cursor + NN;                        // 128
    const size_t ws_needed = (size_t)NE * 8 + (size_t)NN * 128 +
                             (size_t)NE * 128 +
                             (size_t)(3 * NN + 1 + 128) * sizeof(int);

    if (ws_size < ws_needed) {            // insurance: atomic fallback
        k_init<<<2048, 256, 0, stream>>>(x, eps, out);
        k_edges<<<2048, 256, 0, stream>>>(x, ei, ea, out);
        k_linear2<<<NN * 16 / 256, 256, 0, stream>>>(W, b, out);
        return;
    }

    (void)hipMemsetAsync(counts, 0, (size_t)NN * sizeof(int), stream);
    k_cvt_hist<<<2048, 256, 0, stream>>>(ea, x, dst, eab, xb, counts);
    k_scan_block<<<NB, 256, 0, stream>>>(counts, offsets, bsum);
    k_scan_finish<<<256, 256, 0, stream>>>(offsets, bsum, cursor);
    k_scatter<<<1024, 256, 0, stream>>>(dst, src, cursor, ps);
    k_agg_lin<<<NN * 16 / 256, 256, 0, stream>>>(x, xb, eab, offsets, ps, eps,
                                                 W, b, out);
}

// Round 15
// 313.422 us; speedup vs baseline: 1.2760x; 1.2316x over previous
//
#include <hip/hip_runtime.h>

typedef float f4 __attribute__((ext_vector_type(4)));

constexpr int NN = 100000;
constexpr int NE = 1600000;
constexpr int SCAN_BLK = 1024;
constexpr int NB = (NN + SCAN_BLK - 1) / SCAN_BLK;    // 98 scan blocks

__device__ __forceinline__ f4 relu_add(f4 a, f4 b) {
    f4 s = a + b;
    s.x = fmaxf(s.x, 0.f);
    s.y = fmaxf(s.y, 0.f);
    s.z = fmaxf(s.z, 0.f);
    s.w = fmaxf(s.w, 0.f);
    return s;
}

__device__ __forceinline__ f4 bf16x4_to_f4(uint2 u) {
    f4 r;
    r.x = __uint_as_float((u.x & 0xFFFFu) << 16);
    r.y = __uint_as_float(u.x & 0xFFFF0000u);
    r.z = __uint_as_float((u.y & 0xFFFFu) << 16);
    r.w = __uint_as_float(u.y & 0xFFFF0000u);
    return r;
}

__device__ __forceinline__ unsigned f2bf(float f) {
    unsigned u = __float_as_uint(f);
    return (u + 0x7FFFu + ((u >> 16) & 1u)) >> 16;   // round-to-nearest-even
}

__device__ __forceinline__ unsigned pack2bf(float lo, float hi) {
    return f2bf(lo) | (f2bf(hi) << 16);
}

// ---------------- fallback path (used only if ws too small) -------------------

__global__ __launch_bounds__(256) void k_init(const float* __restrict__ x,
                                              const float* __restrict__ eps,
                                              float* __restrict__ out) {
    const float s = 1.0f + eps[0];
    const float4* x4 = (const float4*)x;
    float4* o4 = (float4*)out;
    const int total = NN * 16;
    for (int i = blockIdx.x * blockDim.x + threadIdx.x; i < total;
         i += gridDim.x * blockDim.x) {
        float4 v = x4[i];
        v.x *= s; v.y *= s; v.z *= s; v.w *= s;
        o4[i] = v;
    }
}

__global__ __launch_bounds__(256) void k_edges(const float* __restrict__ x,
                                               const int* __restrict__ ei,
                                               const float* __restrict__ ea,
                                               float* __restrict__ out) {
    const int* dst = ei;
    const int* src = ei + NE;
    const float4* ea4 = (const float4*)ea;
    const float4* x4 = (const float4*)x;
    const int total = NE * 16;
    for (int g = blockIdx.x * blockDim.x + threadIdx.x; g < total;
         g += gridDim.x * blockDim.x) {
        const int e = g >> 4;
        const int c = g & 15;
        const int s = src[e];
        const int d = dst[e];
        float4 a  = ea4[g];
        float4 xv = x4[s * 16 + c];
        float* base = out + d * 64 + c * 4;
        atomicAdd(base + 0, fmaxf(xv.x + a.x, 0.0f));
        atomicAdd(base + 1, fmaxf(xv.y + a.y, 0.0f));
        atomicAdd(base + 2, fmaxf(xv.z + a.z, 0.0f));
        atomicAdd(base + 3, fmaxf(xv.w + a.w, 0.0f));
    }
}

__global__ __launch_bounds__(256) void k_linear2(const float* __restrict__ W,
                                                 const float* __restrict__ bias,
                                                 float* __restrict__ out) {
    __shared__ float Ws[64 * 64];
    __shared__ float bs[64];
    for (int i = threadIdx.x; i < 1024; i += 256)
        ((float4*)Ws)[i] = ((const float4*)W)[i];
    if (threadIdx.x < 16)
        ((float4*)bs)[threadIdx.x] = ((const float4*)bias)[threadIdx.x];
    __syncthreads();

    const int l16 = threadIdx.x & 15;
    const int gid = (blockIdx.x * 256 + threadIdx.x) >> 4;
    const float4* Ws4 = (const float4*)Ws;
    float4* out4 = (float4*)out;

    const float4 h4 = out4[gid * 16 + l16];
    float4 o = ((const float4*)bs)[l16];
#pragma unroll
    for (int d = 0; d < 64; ++d) {
        const int q = d >> 2;
        const int r = d & 3;
        float hd;
        if (r == 0)      hd = __shfl(h4.x, q, 16);
        else if (r == 1) hd = __shfl(h4.y, q, 16);
        else if (r == 2) hd = __shfl(h4.z, q, 16);
        else             hd = __shfl(h4.w, q, 16);
        const float4 w = Ws4[d * 16 + l16];
        o.x = fmaf(hd, w.x, o.x);
        o.y = fmaf(hd, w.y, o.y);
        o.z = fmaf(hd, w.z, o.z);
        o.w = fmaf(hd, w.w, o.w);
    }
    out4[gid * 16 + l16] = o;
}

// ---------------- main path ----------------------------------------------------

__global__ __launch_bounds__(256) void k_hist(const int* __restrict__ dst,
                                              int* __restrict__ counts) {
    const int4* d4 = (const int4*)dst;
    const int total = NE / 4;
    for (int i = blockIdx.x * blockDim.x + threadIdx.x; i < total;
         i += gridDim.x * blockDim.x) {
        const int4 d = d4[i];
        atomicAdd(&counts[d.x], 1);
        atomicAdd(&counts[d.y], 1);
        atomicAdd(&counts[d.z], 1);
        atomicAdd(&counts[d.w], 1);
    }
}

__global__ __launch_bounds__(256) void k_scan_block(const int* __restrict__ counts,
                                                    int* __restrict__ offsets,
                                                    int* __restrict__ bsum) {
    __shared__ int sd[256];
    const int t = threadIdx.x;
    const int base = blockIdx.x * SCAN_BLK;
    int c[4];
    int s = 0;
#pragma unroll
    for (int k = 0; k < 4; ++k) {
        const int i = base + t * 4 + k;
        c[k] = (i < NN) ? counts[i] : 0;
        s += c[k];
    }
    sd[t] = s;
    __syncthreads();
#pragma unroll
    for (int off = 1; off < 256; off <<= 1) {
        int v = (t >= off) ? sd[t - off] : 0;
        __syncthreads();
        sd[t] += v;
        __syncthreads();
    }
    int excl = sd[t] - s;
#pragma unroll
    for (int k = 0; k < 4; ++k) {
        const int i = base + t * 4 + k;
        if (i < NN) offsets[i] = excl;
        excl += c[k];
    }
    if (t == 255) bsum[blockIdx.x] = sd[255];
}

// fused scan of the 98 block sums (redundant per block) + global fixup
__global__ __launch_bounds__(256) void k_scan_finish(int* __restrict__ offsets,
                                                     const int* __restrict__ bsum,
                                                     int* __restrict__ cursor) {
    __shared__ int sd[128];
    const int t = threadIdx.x;
    if (t < 128) {
        const int v = (t < NB) ? bsum[t] : 0;
        sd[t] = v;
    }
    __syncthreads();
#pragma unroll
    for (int off = 1; off < 128; off <<= 1) {
        int u = 0;
        if (t < 128 && t >= off) u = sd[t - off];
        __syncthreads();
        if (t < 128) sd[t] += u;
        __syncthreads();
    }
    // sd now inclusive; exclusive base for block b is sd[b] - bsum[b]
    for (int i = blockIdx.x * blockDim.x + t; i < NN;
         i += gridDim.x * blockDim.x) {
        const int b = i >> 10;
        const int v = offsets[i] + sd[b] - bsum[b];
        offsets[i] = v;
        cursor[i] = v;
    }
    if (blockIdx.x == 0 && t == 0) offsets[NN] = NE;
}

// Edge-order streaming value scatter (R8 structure, corrected):
// ea read SEQUENTIAL (the only big HBM read, full rate); x[src] gather fp32
// (25.6MB, L2/L3-resident); msg rounded to bf16 and written as a 128B row
// into its dst-sorted slot. The 205MB bf16 value buffer FITS IN L3, so these
// random full-line writes mostly stay cache-side. Plain (cached) ops only.
__global__ __launch_bounds__(256) void k_scatter_val(const float* __restrict__ x,
                                                     const int* __restrict__ ei,
                                                     const float* __restrict__ ea,
                                                     int* __restrict__ cursor,
                                                     unsigned short* __restrict__ vals) {
    const int* dst = ei;
    const int* src = ei + NE;
    const int l16 = threadIdx.x & 15;
    const int gid0 = (blockIdx.x * blockDim.x + threadIdx.x) >> 4;
    const int ngrp = (gridDim.x * blockDim.x) >> 4;
    const f4* x4 = (const f4*)x;
    const f4* ea4 = (const f4*)ea;
    uint2* v2 = (uint2*)vals;

    for (int e = gid0; e < NE; e += ngrp) {
        const int d = dst[e];
        const int s = src[e];
        int pos = 0;
        if (l16 == 0) pos = atomicAdd(&cursor[d], 1);
        pos = __shfl(pos, 0, 16);
        const f4 A = ea4[e * 16 + l16];          // streaming, coalesced
        const f4 X = x4[s * 16 + l16];           // cache-resident gather
        const f4 m = relu_add(X, A);
        uint2 o;
        o.x = pack2bf(m.x, m.y);
        o.y = pack2bf(m.z, m.w);
        v2[(size_t)pos * 16 + l16] = o;          // 128B row, full-line writes
    }
}

// Streaming segmented sum + self-term + fused linear.
// One node per 16-lane group (6250 blocks exact). The node's value rows are a
// contiguous range [beg,end) of 128B bf16 rows -> sequential, L3-hit reads.
__global__ __launch_bounds__(256) void k_segsum_lin(const float* __restrict__ x,
                                                    const unsigned short* __restrict__ vals,
                                                    const int* __restrict__ offsets,
                                                    const float* __restrict__ epsp,
                                                    const float* __restrict__ W,
                                                    const float* __restrict__ bias,
                                                    float* __restrict__ out) {
    __shared__ float Ws[64 * 64];
    __shared__ float bs[64];
    for (int i = threadIdx.x; i < 1024; i += 256)
        ((float4*)Ws)[i] = ((const float4*)W)[i];
    if (threadIdx.x < 16)
        ((float4*)bs)[threadIdx.x] = ((const float4*)bias)[threadIdx.x];
    __syncthreads();

    const float epsv = 1.0f + epsp[0];
    const int l16 = threadIdx.x & 15;
    const int n = (blockIdx.x * 256 + threadIdx.x) >> 4;   // node id, < NN exact
    const f4* x4 = (const f4*)x;
    const uint2* v2 = (const uint2*)vals;
    const f4* Ws4 = (const f4*)Ws;
    f4* out4 = (f4*)out;

    const int beg = offsets[n];
    const int end = offsets[n + 1];
    f4 acc = {0.f, 0.f, 0.f, 0.f};

    int j = beg;
    for (; j + 4 <= end; j += 4) {               // sequential 128B rows
        const uint2 u0 = v2[(size_t)(j + 0) * 16 + l16];
        const uint2 u1 = v2[(size_t)(j + 1) * 16 + l16];
        const uint2 u2 = v2[(size_t)(j + 2) * 16 + l16];
        const uint2 u3 = v2[(size_t)(j + 3) * 16 + l16];
        acc += bf16x4_to_f4(u0) + bf16x4_to_f4(u1) +
               bf16x4_to_f4(u2) + bf16x4_to_f4(u3);
    }
    for (; j < end; ++j)
        acc += bf16x4_to_f4(v2[(size_t)j * 16 + l16]);

    // self term from exact fp32 x
    const f4 xs = x4[n * 16 + l16];
    f4 h;
    h.x = fmaf(xs.x, epsv, acc.x);
    h.y = fmaf(xs.y, epsv, acc.y);
    h.z = fmaf(xs.z, epsv, acc.z);
    h.w = fmaf(xs.w, epsv, acc.w);

    // fused linear: o[l16*4+k] = b + sum_d h[d] * W[d][l16*4+k]
    f4 o = ((const f4*)bs)[l16];
#pragma unroll
    for (int d = 0; d < 64; ++d) {
        const int q = d >> 2;
        const int r = d & 3;
        float hd;
        if (r == 0)      hd = __shfl(h.x, q, 16);
        else if (r == 1) hd = __shfl(h.y, q, 16);
        else if (r == 2) hd = __shfl(h.z, q, 16);
        else             hd = __shfl(h.w, q, 16);
        const f4 w = Ws4[d * 16 + l16];
        o.x = fmaf(hd, w.x, o.x);
        o.y = fmaf(hd, w.y, o.y);
        o.z = fmaf(hd, w.z, o.z);
        o.w = fmaf(hd, w.w, o.w);
    }
    out4[n * 16 + l16] = o;
}

extern "C" void kernel_launch(void* const* d_in, const int* in_sizes, int n_in,
                              void* d_out, int out_size, void* d_ws, size_t ws_size,
                              hipStream_t stream) {
    const float* x   = (const float*)d_in[0];
    const int*   ei  = (const int*)d_in[1];
    const float* ea  = (const float*)d_in[2];
    const float* eps = (const float*)d_in[3];
    const float* W   = (const float*)d_in[4];
    const float* b   = (const float*)d_in[5];
    float* out = (float*)d_out;

    const int* dst = ei;        // edge_index[0]

    // workspace layout: vals (bf16, 16B-aligned at base), then ints
    unsigned short* vals = (unsigned short*)d_ws;      // NE*64 bf16 (204.8 MB)
    int* counts  = (int*)(vals + (size_t)NE * 64);     // NN
    int* offsets = counts + NN;                        // NN + 1
    int* cursor  = offsets + NN + 1;                   // NN
    int* bsum    = cursor + NN;                        // 128
    const size_t ws_needed = (size_t)NE * 128 +
                             (size_t)(3 * NN + 1 + 128) * sizeof(int);

    if (ws_size < ws_needed) {            // insurance: atomic fallback
        k_init<<<2048, 256, 0, stream>>>(x, eps, out);
        k_edges<<<2048, 256, 0, stream>>>(x, ei, ea, out);
        k_linear2<<<NN * 16 / 256, 256, 0, stream>>>(W, b, out);
        return;
    }

    (void)hipMemsetAsync(counts, 0, (size_t)NN * sizeof(int), stream);
    k_hist<<<1024, 256, 0, stream>>>(dst, counts);
    k_scan_block<<<NB, 256, 0, stream>>>(counts, offsets, bsum);
    k_scan_finish<<<256, 256, 0, stream>>>(offsets, bsum, cursor);
    k_scatter_val<<<4096, 256, 0, stream>>>(x, ei, ea, cursor, vals);
    k_segsum_lin<<<NN * 16 / 256, 256, 0, stream>>>(x, vals, offsets, eps,
                                                    W, b, out);
}

// Round 16
// 296.922 us; speedup vs baseline: 1.3469x; 1.0556x over previous
//
#include <hip/hip_runtime.h>

typedef float f4 __attribute__((ext_vector_type(4)));

constexpr int NN = 100000;
constexpr int NE = 1600000;
constexpr int SCAN_BLK = 1024;
constexpr int NB = (NN + SCAN_BLK - 1) / SCAN_BLK;    // 98 scan blocks

__device__ __forceinline__ f4 relu_add(f4 a, f4 b) {
    f4 s = a + b;
    s.x = fmaxf(s.x, 0.f);
    s.y = fmaxf(s.y, 0.f);
    s.z = fmaxf(s.z, 0.f);
    s.w = fmaxf(s.w, 0.f);
    return s;
}

__device__ __forceinline__ f4 bf16x4_to_f4(uint2 u) {
    f4 r;
    r.x = __uint_as_float((u.x & 0xFFFFu) << 16);
    r.y = __uint_as_float(u.x & 0xFFFF0000u);
    r.z = __uint_as_float((u.y & 0xFFFFu) << 16);
    r.w = __uint_as_float(u.y & 0xFFFF0000u);
    return r;
}

__device__ __forceinline__ unsigned f2bf(float f) {
    unsigned u = __float_as_uint(f);
    return (u + 0x7FFFu + ((u >> 16) & 1u)) >> 16;   // round-to-nearest-even
}

__device__ __forceinline__ unsigned pack2bf(float lo, float hi) {
    return f2bf(lo) | (f2bf(hi) << 16);
}

// ---------------- fallback path (used only if ws too small) -------------------

__global__ __launch_bounds__(256) void k_init(const float* __restrict__ x,
                                              const float* __restrict__ eps,
                                              float* __restrict__ out) {
    const float s = 1.0f + eps[0];
    const float4* x4 = (const float4*)x;
    float4* o4 = (float4*)out;
    const int total = NN * 16;
    for (int i = blockIdx.x * blockDim.x + threadIdx.x; i < total;
         i += gridDim.x * blockDim.x) {
        float4 v = x4[i];
        v.x *= s; v.y *= s; v.z *= s; v.w *= s;
        o4[i] = v;
    }
}

__global__ __launch_bounds__(256) void k_edges(const float* __restrict__ x,
                                               const int* __restrict__ ei,
                                               const float* __restrict__ ea,
                                               float* __restrict__ out) {
    const int* dst = ei;
    const int* src = ei + NE;
    const float4* ea4 = (const float4*)ea;
    const float4* x4 = (const float4*)x;
    const int total = NE * 16;
    for (int g = blockIdx.x * blockDim.x + threadIdx.x; g < total;
         g += gridDim.x * blockDim.x) {
        const int e = g >> 4;
        const int c = g & 15;
        const int s = src[e];
        const int d = dst[e];
        float4 a  = ea4[g];
        float4 xv = x4[s * 16 + c];
        float* base = out + d * 64 + c * 4;
        atomicAdd(base + 0, fmaxf(xv.x + a.x, 0.0f));
        atomicAdd(base + 1, fmaxf(xv.y + a.y, 0.0f));
        atomicAdd(base + 2, fmaxf(xv.z + a.z, 0.0f));
        atomicAdd(base + 3, fmaxf(xv.w + a.w, 0.0f));
    }
}

__global__ __launch_bounds__(256) void k_linear2(const float* __restrict__ W,
                                                 const float* __restrict__ bias,
                                                 float* __restrict__ out) {
    __shared__ float Ws[64 * 64];
    __shared__ float bs[64];
    for (int i = threadIdx.x; i < 1024; i += 256)
        ((float4*)Ws)[i] = ((const float4*)W)[i];
    if (threadIdx.x < 16)
        ((float4*)bs)[threadIdx.x] = ((const float4*)bias)[threadIdx.x];
    __syncthreads();

    const int l16 = threadIdx.x & 15;
    const int gid = (blockIdx.x * 256 + threadIdx.x) >> 4;
    const float4* Ws4 = (const float4*)Ws;
    float4* out4 = (float4*)out;

    const float4 h4 = out4[gid * 16 + l16];
    float4 o = ((const float4*)bs)[l16];
#pragma unroll
    for (int d = 0; d < 64; ++d) {
        const int q = d >> 2;
        const int r = d & 3;
        float hd;
        if (r == 0)      hd = __shfl(h4.x, q, 16);
        else if (r == 1) hd = __shfl(h4.y, q, 16);
        else if (r == 2) hd = __shfl(h4.z, q, 16);
        else             hd = __shfl(h4.w, q, 16);
        const float4 w = Ws4[d * 16 + l16];
        o.x = fmaf(hd, w.x, o.x);
        o.y = fmaf(hd, w.y, o.y);
        o.z = fmaf(hd, w.z, o.z);
        o.w = fmaf(hd, w.w, o.w);
    }
    out4[gid * 16 + l16] = o;
}

// ---------------- main path ----------------------------------------------------

// rank pass: r[e] = running index of edge e within its dst's segment.
// Side effect: cursor[] ends up holding the per-node degree (histogram free).
__global__ __launch_bounds__(256) void k_rank(const int* __restrict__ dst,
                                              int* __restrict__ cursor,
                                              int* __restrict__ rank) {
    const int4* d4 = (const int4*)dst;
    int4* r4 = (int4*)rank;
    const int total = NE / 4;
    for (int i = blockIdx.x * blockDim.x + threadIdx.x; i < total;
         i += gridDim.x * blockDim.x) {
        const int4 d = d4[i];
        int4 r;
        r.x = atomicAdd(&cursor[d.x], 1);
        r.y = atomicAdd(&cursor[d.y], 1);
        r.z = atomicAdd(&cursor[d.z], 1);
        r.w = atomicAdd(&cursor[d.w], 1);
        r4[i] = r;
    }
}

__global__ __launch_bounds__(256) void k_scan_block(const int* __restrict__ counts,
                                                    int* __restrict__ offsets,
                                                    int* __restrict__ bsum) {
    __shared__ int sd[256];
    const int t = threadIdx.x;
    const int base = blockIdx.x * SCAN_BLK;
    int c[4];
    int s = 0;
#pragma unroll
    for (int k = 0; k < 4; ++k) {
        const int i = base + t * 4 + k;
        c[k] = (i < NN) ? counts[i] : 0;
        s += c[k];
    }
    sd[t] = s;
    __syncthreads();
#pragma unroll
    for (int off = 1; off < 256; off <<= 1) {
        int v = (t >= off) ? sd[t - off] : 0;
        __syncthreads();
        sd[t] += v;
        __syncthreads();
    }
    int excl = sd[t] - s;
#pragma unroll
    for (int k = 0; k < 4; ++k) {
        const int i = base + t * 4 + k;
        if (i < NN) offsets[i] = excl;
        excl += c[k];
    }
    if (t == 255) bsum[blockIdx.x] = sd[255];
}

// fused scan of the 98 block sums (redundant per block) + global fixup
__global__ __launch_bounds__(256) void k_scan_finish(int* __restrict__ offsets,
                                                     const int* __restrict__ bsum) {
    __shared__ int sd[128];
    const int t = threadIdx.x;
    if (t < 128) {
        const int v = (t < NB) ? bsum[t] : 0;
        sd[t] = v;
    }
    __syncthreads();
#pragma unroll
    for (int off = 1; off < 128; off <<= 1) {
        int u = 0;
        if (t < 128 && t >= off) u = sd[t - off];
        __syncthreads();
        if (t < 128) sd[t] += u;
        __syncthreads();
    }
    // sd now inclusive; exclusive base for block b is sd[b] - bsum[b]
    for (int i = blockIdx.x * blockDim.x + t; i < NN;
         i += gridDim.x * blockDim.x) {
        const int b = i >> 10;
        offsets[i] += sd[b] - bsum[b];
    }
    if (blockIdx.x == 0 && t == 0) offsets[NN] = NE;
}

// ATOMIC-FREE edge-order streaming value scatter.
// slot = offsets[dst[e]] + rank[e] — pure loads (offsets: 400KB L2-resident;
// rank: streamed). No atomics, no shfl: every iteration is independent, so
// the compiler can software-pipeline the 425MB ea/x stream at full rate.
// Writes bf16 128B rows into the dst-sorted 205MB L3-resident value buffer.
__global__ __launch_bounds__(256) void k_scatter_val(const float* __restrict__ x,
                                                     const int* __restrict__ ei,
                                                     const float* __restrict__ ea,
                                                     const int* __restrict__ offsets,
                                                     const int* __restrict__ rank,
                                                     unsigned short* __restrict__ vals) {
    const int* dst = ei;
    const int* src = ei + NE;
    const int l16 = threadIdx.x & 15;
    const int gid0 = (blockIdx.x * blockDim.x + threadIdx.x) >> 4;
    const int ngrp = (gridDim.x * blockDim.x) >> 4;
    const f4* x4 = (const f4*)x;
    const f4* ea4 = (const f4*)ea;
    uint2* v2 = (uint2*)vals;

    const int nbatch = NE / 2;               // 2 edges per group-iteration
    for (int bi = gid0; bi < nbatch; bi += ngrp) {
        const int e0 = 2 * bi;
        const int e1 = 2 * bi + 1;
        const int d0 = dst[e0], d1 = dst[e1];
        const int s0 = src[e0], s1 = src[e1];
        const int slot0 = offsets[d0] + rank[e0];
        const int slot1 = offsets[d1] + rank[e1];
        const f4 A0 = ea4[(size_t)e0 * 16 + l16];
        const f4 X0 = x4[(size_t)s0 * 16 + l16];
        const f4 A1 = ea4[(size_t)e1 * 16 + l16];
        const f4 X1 = x4[(size_t)s1 * 16 + l16];
        const f4 m0 = relu_add(X0, A0);
        const f4 m1 = relu_add(X1, A1);
        uint2 o0, o1;
        o0.x = pack2bf(m0.x, m0.y);
        o0.y = pack2bf(m0.z, m0.w);
        o1.x = pack2bf(m1.x, m1.y);
        o1.y = pack2bf(m1.z, m1.w);
        v2[(size_t)slot0 * 16 + l16] = o0;
        v2[(size_t)slot1 * 16 + l16] = o1;
    }
}

// Streaming segmented sum + self-term + fused linear (R15 verified).
// One node per 16-lane group (6250 blocks exact); contiguous bf16 rows.
__global__ __launch_bounds__(256) void k_segsum_lin(const float* __restrict__ x,
                                                    const unsigned short* __restrict__ vals,
                                                    const int* __restrict__ offsets,
                                                    const float* __restrict__ epsp,
                                                    const float* __restrict__ W,
                                                    const float* __restrict__ bias,
                                                    float* __restrict__ out) {
    __shared__ float Ws[64 * 64];
    __shared__ float bs[64];
    for (int i = threadIdx.x; i < 1024; i += 256)
        ((float4*)Ws)[i] = ((const float4*)W)[i];
    if (threadIdx.x < 16)
        ((float4*)bs)[threadIdx.x] = ((const float4*)bias)[threadIdx.x];
    __syncthreads();

    const float epsv = 1.0f + epsp[0];
    const int l16 = threadIdx.x & 15;
    const int n = (blockIdx.x * 256 + threadIdx.x) >> 4;   // node id, < NN exact
    const f4* x4 = (const f4*)x;
    const uint2* v2 = (const uint2*)vals;
    const f4* Ws4 = (const f4*)Ws;
    f4* out4 = (f4*)out;

    const int beg = offsets[n];
    const int end = offsets[n + 1];
    f4 acc = {0.f, 0.f, 0.f, 0.f};

    int j = beg;
    for (; j + 4 <= end; j += 4) {               // sequential 128B rows
        const uint2 u0 = v2[(size_t)(j + 0) * 16 + l16];
        const uint2 u1 = v2[(size_t)(j + 1) * 16 + l16];
        const uint2 u2 = v2[(size_t)(j + 2) * 16 + l16];
        const uint2 u3 = v2[(size_t)(j + 3) * 16 + l16];
        acc += bf16x4_to_f4(u0) + bf16x4_to_f4(u1) +
               bf16x4_to_f4(u2) + bf16x4_to_f4(u3);
    }
    for (; j < end; ++j)
        acc += bf16x4_to_f4(v2[(size_t)j * 16 + l16]);

    // self term from exact fp32 x
    const f4 xs = x4[n * 16 + l16];
    f4 h;
    h.x = fmaf(xs.x, epsv, acc.x);
    h.y = fmaf(xs.y, epsv, acc.y);
    h.z = fmaf(xs.z, epsv, acc.z);
    h.w = fmaf(xs.w, epsv, acc.w);

    // fused linear: o[l16*4+k] = b + sum_d h[d] * W[d][l16*4+k]
    f4 o = ((const f4*)bs)[l16];
#pragma unroll
    for (int d = 0; d < 64; ++d) {
        const int q = d >> 2;
        const int r = d & 3;
        float hd;
        if (r == 0)      hd = __shfl(h.x, q, 16);
        else if (r == 1) hd = __shfl(h.y, q, 16);
        else if (r == 2) hd = __shfl(h.z, q, 16);
        else             hd = __shfl(h.w, q, 16);
        const f4 w = Ws4[d * 16 + l16];
        o.x = fmaf(hd, w.x, o.x);
        o.y = fmaf(hd, w.y, o.y);
        o.z = fmaf(hd, w.z, o.z);
        o.w = fmaf(hd, w.w, o.w);
    }
    out4[n * 16 + l16] = o;
}

extern "C" void kernel_launch(void* const* d_in, const int* in_sizes, int n_in,
                              void* d_out, int out_size, void* d_ws, size_t ws_size,
                              hipStream_t stream) {
    const float* x   = (const float*)d_in[0];
    const int*   ei  = (const int*)d_in[1];
    const float* ea  = (const float*)d_in[2];
    const float* eps = (const float*)d_in[3];
    const float* W   = (const float*)d_in[4];
    const float* b   = (const float*)d_in[5];
    float* out = (float*)d_out;

    const int* dst = ei;        // edge_index[0]

    // workspace layout: vals (16B-aligned at base), rank, ints
    unsigned short* vals = (unsigned short*)d_ws;      // NE*64 bf16 (204.8 MB)
    int* rank    = (int*)(vals + (size_t)NE * 64);     // NE (6.4 MB)
    int* cursor  = rank + NE;                          // NN (counts after k_rank)
    int* offsets = cursor + NN;                        // NN + 1
    int* bsum    = offsets + NN + 1;                   // 128
    const size_t ws_needed = (size_t)NE * 128 + (size_t)NE * 4 +
                             (size_t)(2 * NN + 1 + 128) * sizeof(int);

    if (ws_size < ws_needed) {            // insurance: atomic fallback
        k_init<<<2048, 256, 0, stream>>>(x, eps, out);
        k_edges<<<2048, 256, 0, stream>>>(x, ei, ea, out);
        k_linear2<<<NN * 16 / 256, 256, 0, stream>>>(W, b, out);
        return;
    }

    (void)hipMemsetAsync(cursor, 0, (size_t)NN * sizeof(int), stream);
    k_rank<<<1024, 256, 0, stream>>>(dst, cursor, rank);
    k_scan_block<<<NB, 256, 0, stream>>>(cursor, offsets, bsum);
    k_scan_finish<<<256, 256, 0, stream>>>(offsets, bsum);
    k_scatter_val<<<4096, 256, 0, stream>>>(x, ei, ea, offsets, rank, vals);
    k_segsum_lin<<<NN * 16 / 256, 256, 0, stream>>>(x, vals, offsets, eps,
                                                    W, b, out);
}

// Round 17
// 282.069 us; speedup vs baseline: 1.4178x; 1.0527x over previous
//
#include <hip/hip_runtime.h>

typedef float f4 __attribute__((ext_vector_type(4)));

constexpr int NN = 100000;
constexpr int NE = 1600000;
constexpr int SCAN_BLK = 1024;
constexpr int NB = (NN + SCAN_BLK - 1) / SCAN_BLK;    // 98 scan blocks

__device__ __forceinline__ f4 relu_add(f4 a, f4 b) {
    f4 s = a + b;
    s.x = fmaxf(s.x, 0.f);
    s.y = fmaxf(s.y, 0.f);
    s.z = fmaxf(s.z, 0.f);
    s.w = fmaxf(s.w, 0.f);
    return s;
}

__device__ __forceinline__ f4 bf16x4_to_f4(uint2 u) {
    f4 r;
    r.x = __uint_as_float((u.x & 0xFFFFu) << 16);
    r.y = __uint_as_float(u.x & 0xFFFF0000u);
    r.z = __uint_as_float((u.y & 0xFFFFu) << 16);
    r.w = __uint_as_float(u.y & 0xFFFF0000u);
    return r;
}

__device__ __forceinline__ unsigned f2bf(float f) {
    unsigned u = __float_as_uint(f);
    return (u + 0x7FFFu + ((u >> 16) & 1u)) >> 16;   // round-to-nearest-even
}

__device__ __forceinline__ unsigned pack2bf(float lo, float hi) {
    return f2bf(lo) | (f2bf(hi) << 16);
}

// ---------------- fallback path (used only if ws too small) -------------------

__global__ __launch_bounds__(256) void k_init(const float* __restrict__ x,
                                              const float* __restrict__ eps,
                                              float* __restrict__ out) {
    const float s = 1.0f + eps[0];
    const float4* x4 = (const float4*)x;
    float4* o4 = (float4*)out;
    const int total = NN * 16;
    for (int i = blockIdx.x * blockDim.x + threadIdx.x; i < total;
         i += gridDim.x * blockDim.x) {
        float4 v = x4[i];
        v.x *= s; v.y *= s; v.z *= s; v.w *= s;
        o4[i] = v;
    }
}

__global__ __launch_bounds__(256) void k_edges(const float* __restrict__ x,
                                               const int* __restrict__ ei,
                                               const float* __restrict__ ea,
                                               float* __restrict__ out) {
    const int* dst = ei;
    const int* src = ei + NE;
    const float4* ea4 = (const float4*)ea;
    const float4* x4 = (const float4*)x;
    const int total = NE * 16;
    for (int g = blockIdx.x * blockDim.x + threadIdx.x; g < total;
         g += gridDim.x * blockDim.x) {
        const int e = g >> 4;
        const int c = g & 15;
        const int s = src[e];
        const int d = dst[e];
        float4 a  = ea4[g];
        float4 xv = x4[s * 16 + c];
        float* base = out + d * 64 + c * 4;
        atomicAdd(base + 0, fmaxf(xv.x + a.x, 0.0f));
        atomicAdd(base + 1, fmaxf(xv.y + a.y, 0.0f));
        atomicAdd(base + 2, fmaxf(xv.z + a.z, 0.0f));
        atomicAdd(base + 3, fmaxf(xv.w + a.w, 0.0f));
    }
}

__global__ __launch_bounds__(256) void k_linear2(const float* __restrict__ W,
                                                 const float* __restrict__ bias,
                                                 float* __restrict__ out) {
    __shared__ float Ws[64 * 64];
    __shared__ float bs[64];
    for (int i = threadIdx.x; i < 1024; i += 256)
        ((float4*)Ws)[i] = ((const float4*)W)[i];
    if (threadIdx.x < 16)
        ((float4*)bs)[threadIdx.x] = ((const float4*)bias)[threadIdx.x];
    __syncthreads();

    const int l16 = threadIdx.x & 15;
    const int gid = (blockIdx.x * 256 + threadIdx.x) >> 4;
    const float4* Ws4 = (const float4*)Ws;
    float4* out4 = (float4*)out;

    const float4 h4 = out4[gid * 16 + l16];
    float4 o = ((const float4*)bs)[l16];
#pragma unroll
    for (int d = 0; d < 64; ++d) {
        const int q = d >> 2;
        const int r = d & 3;
        float hd;
        if (r == 0)      hd = __shfl(h4.x, q, 16);
        else if (r == 1) hd = __shfl(h4.y, q, 16);
        else if (r == 2) hd = __shfl(h4.z, q, 16);
        else             hd = __shfl(h4.w, q, 16);
        const float4 w = Ws4[d * 16 + l16];
        o.x = fmaf(hd, w.x, o.x);
        o.y = fmaf(hd, w.y, o.y);
        o.z = fmaf(hd, w.z, o.z);
        o.w = fmaf(hd, w.w, o.w);
    }
    out4[gid * 16 + l16] = o;
}

// ---------------- main path ----------------------------------------------------

// fused: rank pass (side effect: cursor[] = per-node degree) + x -> bf16 table.
// The streaming cvt rides under the atomic-latency-bound rank loop.
__global__ __launch_bounds__(256) void k_rank_cvt(const int* __restrict__ dst,
                                                  const float* __restrict__ x,
                                                  int* __restrict__ cursor,
                                                  int* __restrict__ rank,
                                                  unsigned short* __restrict__ xb) {
    const int tid = blockIdx.x * blockDim.x + threadIdx.x;
    const int nthr = gridDim.x * blockDim.x;

    // x conversion: 8 floats in (32B), 8 bf16 out (16B) per iteration
    const f4* x4 = (const f4*)x;
    uint4* xbo = (uint4*)xb;
    const int xtotal = NN * 8;
    for (int i = tid; i < xtotal; i += nthr) {
        const f4 a = x4[2 * i];
        const f4 b = x4[2 * i + 1];
        uint4 o;
        o.x = pack2bf(a.x, a.y);
        o.y = pack2bf(a.z, a.w);
        o.z = pack2bf(b.x, b.y);
        o.w = pack2bf(b.z, b.w);
        xbo[i] = o;
    }

    const int4* d4 = (const int4*)dst;
    int4* r4 = (int4*)rank;
    const int total = NE / 4;
    for (int i = tid; i < total; i += nthr) {
        const int4 d = d4[i];
        int4 r;
        r.x = atomicAdd(&cursor[d.x], 1);
        r.y = atomicAdd(&cursor[d.y], 1);
        r.z = atomicAdd(&cursor[d.z], 1);
        r.w = atomicAdd(&cursor[d.w], 1);
        r4[i] = r;
    }
}

__global__ __launch_bounds__(256) void k_scan_block(const int* __restrict__ counts,
                                                    int* __restrict__ offsets,
                                                    int* __restrict__ bsum) {
    __shared__ int sd[256];
    const int t = threadIdx.x;
    const int base = blockIdx.x * SCAN_BLK;
    int c[4];
    int s = 0;
#pragma unroll
    for (int k = 0; k < 4; ++k) {
        const int i = base + t * 4 + k;
        c[k] = (i < NN) ? counts[i] : 0;
        s += c[k];
    }
    sd[t] = s;
    __syncthreads();
#pragma unroll
    for (int off = 1; off < 256; off <<= 1) {
        int v = (t >= off) ? sd[t - off] : 0;
        __syncthreads();
        sd[t] += v;
        __syncthreads();
    }
    int excl = sd[t] - s;
#pragma unroll
    for (int k = 0; k < 4; ++k) {
        const int i = base + t * 4 + k;
        if (i < NN) offsets[i] = excl;
        excl += c[k];
    }
    if (t == 255) bsum[blockIdx.x] = sd[255];
}

// fused scan of the 98 block sums (redundant per block) + global fixup
__global__ __launch_bounds__(256) void k_scan_finish(int* __restrict__ offsets,
                                                     const int* __restrict__ bsum) {
    __shared__ int sd[128];
    const int t = threadIdx.x;
    if (t < 128) {
        const int v = (t < NB) ? bsum[t] : 0;
        sd[t] = v;
    }
    __syncthreads();
#pragma unroll
    for (int off = 1; off < 128; off <<= 1) {
        int u = 0;
        if (t < 128 && t >= off) u = sd[t - off];
        __syncthreads();
        if (t < 128) sd[t] += u;
        __syncthreads();
    }
    // sd now inclusive; exclusive base for block b is sd[b] - bsum[b]
    for (int i = blockIdx.x * blockDim.x + t; i < NN;
         i += gridDim.x * blockDim.x) {
        const int b = i >> 10;
        offsets[i] += sd[b] - bsum[b];
    }
    if (blockIdx.x == 0 && t == 0) offsets[NN] = NE;
}

// ATOMIC-FREE edge-order streaming value scatter, 4 edges per iteration.
// slot = offsets[dst[e]] + rank[e] — pure loads. ea read is sequential fp32;
// x gathered from the 12.8MB bf16 table (halves gather traffic vs fp32).
// Writes bf16 128B rows into the dst-sorted 205MB L3-resident value buffer.
__global__ __launch_bounds__(256) void k_scatter_val(const unsigned short* __restrict__ xb,
                                                     const int* __restrict__ ei,
                                                     const float* __restrict__ ea,
                                                     const int* __restrict__ offsets,
                                                     const int* __restrict__ rank,
                                                     unsigned short* __restrict__ vals) {
    const int* dst = ei;
    const int* src = ei + NE;
    const int l16 = threadIdx.x & 15;
    const int gid0 = (blockIdx.x * blockDim.x + threadIdx.x) >> 4;
    const int ngrp = (gridDim.x * blockDim.x) >> 4;
    const f4* ea4 = (const f4*)ea;
    uint2* v2 = (uint2*)vals;

    const int nbatch = NE / 4;               // 4 edges per group-iteration
    for (int bi = gid0; bi < nbatch; bi += ngrp) {
        const int e0 = 4 * bi, e1 = e0 + 1, e2 = e0 + 2, e3 = e0 + 3;
        const int d0 = dst[e0], d1 = dst[e1], d2 = dst[e2], d3 = dst[e3];
        const int s0 = src[e0], s1 = src[e1], s2 = src[e2], s3 = src[e3];
        const int slot0 = offsets[d0] + rank[e0];
        const int slot1 = offsets[d1] + rank[e1];
        const int slot2 = offsets[d2] + rank[e2];
        const int slot3 = offsets[d3] + rank[e3];
        const f4 A0 = ea4[(size_t)e0 * 16 + l16];
        const f4 A1 = ea4[(size_t)e1 * 16 + l16];
        const f4 A2 = ea4[(size_t)e2 * 16 + l16];
        const f4 A3 = ea4[(size_t)e3 * 16 + l16];
        const uint2 xu0 = *(const uint2*)&xb[(size_t)s0 * 64 + l16 * 4];
        const uint2 xu1 = *(const uint2*)&xb[(size_t)s1 * 64 + l16 * 4];
        const uint2 xu2 = *(const uint2*)&xb[(size_t)s2 * 64 + l16 * 4];
        const uint2 xu3 = *(const uint2*)&xb[(size_t)s3 * 64 + l16 * 4];
        const f4 m0 = relu_add(bf16x4_to_f4(xu0), A0);
        const f4 m1 = relu_add(bf16x4_to_f4(xu1), A1);
        const f4 m2 = relu_add(bf16x4_to_f4(xu2), A2);
        const f4 m3 = relu_add(bf16x4_to_f4(xu3), A3);
        uint2 o0, o1, o2, o3;
        o0.x = pack2bf(m0.x, m0.y); o0.y = pack2bf(m0.z, m0.w);
        o1.x = pack2bf(m1.x, m1.y); o1.y = pack2bf(m1.z, m1.w);
        o2.x = pack2bf(m2.x, m2.y); o2.y = pack2bf(m2.z, m2.w);
        o3.x = pack2bf(m3.x, m3.y); o3.y = pack2bf(m3.z, m3.w);
        v2[(size_t)slot0 * 16 + l16] = o0;
        v2[(size_t)slot1 * 16 + l16] = o1;
        v2[(size_t)slot2 * 16 + l16] = o2;
        v2[(size_t)slot3 * 16 + l16] = o3;
    }
}

// Streaming segmented sum + self-term + fused linear (R15 verified).
// One node per 16-lane group (6250 blocks exact); contiguous bf16 rows.
__global__ __launch_bounds__(256) void k_segsum_lin(const float* __restrict__ x,
                                                    const unsigned short* __restrict__ vals,
                                                    const int* __restrict__ offsets,
                                                    const float* __restrict__ epsp,
                                                    const float* __restrict__ W,
                                                    const float* __restrict__ bias,
                                                    float* __restrict__ out) {
    __shared__ float Ws[64 * 64];
    __shared__ float bs[64];
    for (int i = threadIdx.x; i < 1024; i += 256)
        ((float4*)Ws)[i] = ((const float4*)W)[i];
    if (threadIdx.x < 16)
        ((float4*)bs)[threadIdx.x] = ((const float4*)bias)[threadIdx.x];
    __syncthreads();

    const float epsv = 1.0f + epsp[0];
    const int l16 = threadIdx.x & 15;
    const int n = (blockIdx.x * 256 + threadIdx.x) >> 4;   // node id, < NN exact
    const f4* x4 = (const f4*)x;
    const uint2* v2 = (const uint2*)vals;
    const f4* Ws4 = (const f4*)Ws;
    f4* out4 = (f4*)out;

    const int beg = offsets[n];
    const int end = offsets[n + 1];
    f4 acc = {0.f, 0.f, 0.f, 0.f};

    int j = beg;
    for (; j + 4 <= end; j += 4) {               // sequential 128B rows
        const uint2 u0 = v2[(size_t)(j + 0) * 16 + l16];
        const uint2 u1 = v2[(size_t)(j + 1) * 16 + l16];
        const uint2 u2 = v2[(size_t)(j + 2) * 16 + l16];
        const uint2 u3 = v2[(size_t)(j + 3) * 16 + l16];
        acc += bf16x4_to_f4(u0) + bf16x4_to_f4(u1) +
               bf16x4_to_f4(u2) + bf16x4_to_f4(u3);
    }
    for (; j < end; ++j)
        acc += bf16x4_to_f4(v2[(size_t)j * 16 + l16]);

    // self term from exact fp32 x
    const f4 xs = x4[n * 16 + l16];
    f4 h;
    h.x = fmaf(xs.x, epsv, acc.x);
    h.y = fmaf(xs.y, epsv, acc.y);
    h.z = fmaf(xs.z, epsv, acc.z);
    h.w = fmaf(xs.w, epsv, acc.w);

    // fused linear: o[l16*4+k] = b + sum_d h[d] * W[d][l16*4+k]
    f4 o = ((const f4*)bs)[l16];
#pragma unroll
    for (int d = 0; d < 64; ++d) {
        const int q = d >> 2;
        const int r = d & 3;
        float hd;
        if (r == 0)      hd = __shfl(h.x, q, 16);
        else if (r == 1) hd = __shfl(h.y, q, 16);
        else if (r == 2) hd = __shfl(h.z, q, 16);
        else             hd = __shfl(h.w, q, 16);
        const f4 w = Ws4[d * 16 + l16];
        o.x = fmaf(hd, w.x, o.x);
        o.y = fmaf(hd, w.y, o.y);
        o.z = fmaf(hd, w.z, o.z);
        o.w = fmaf(hd, w.w, o.w);
    }
    out4[n * 16 + l16] = o;
}

extern "C" void kernel_launch(void* const* d_in, const int* in_sizes, int n_in,
                              void* d_out, int out_size, void* d_ws, size_t ws_size,
                              hipStream_t stream) {
    const float* x   = (const float*)d_in[0];
    const int*   ei  = (const int*)d_in[1];
    const float* ea  = (const float*)d_in[2];
    const float* eps = (const float*)d_in[3];
    const float* W   = (const float*)d_in[4];
    const float* b   = (const float*)d_in[5];
    float* out = (float*)d_out;

    const int* dst = ei;        // edge_index[0]

    // workspace layout: vals (16B-aligned at base), xb, rank, ints
    unsigned short* vals = (unsigned short*)d_ws;      // NE*64 bf16 (204.8 MB)
    unsigned short* xb   = vals + (size_t)NE * 64;     // NN*64 bf16 (12.8 MB)
    int* rank    = (int*)(xb + (size_t)NN * 64);       // NE (6.4 MB)
    int* cursor  = rank + NE;                          // NN (counts after rank)
    int* offsets = cursor + NN;                        // NN + 1
    int* bsum    = offsets + NN + 1;                   // 128
    const size_t ws_needed = (size_t)NE * 128 + (size_t)NN * 128 +
                             (size_t)NE * 4 +
                             (size_t)(2 * NN + 1 + 128) * sizeof(int);

    if (ws_size < ws_needed) {            // insurance: atomic fallback
        k_init<<<2048, 256, 0, stream>>>(x, eps, out);
        k_edges<<<2048, 256, 0, stream>>>(x, ei, ea, out);
        k_linear2<<<NN * 16 / 256, 256, 0, stream>>>(W, b, out);
        return;
    }

    (void)hipMemsetAsync(cursor, 0, (size_t)NN * sizeof(int), stream);
    k_rank_cvt<<<1024, 256, 0, stream>>>(dst, x, cursor, rank, xb);
    k_scan_block<<<NB, 256, 0, stream>>>(cursor, offsets, bsum);
    k_scan_finish<<<256, 256, 0, stream>>>(offsets, bsum);
    k_scatter_val<<<4096, 256, 0, stream>>>(xb, ei, ea, offsets, rank, vals);
    k_segsum_lin<<<NN * 16 / 256, 256, 0, stream>>>(x, vals, offsets, eps,
                                                    W, b, out);
}